// Round 1
// baseline (973.810 us; speedup 1.0000x reference)
//
#include <hip/hip_runtime.h>

// ---------------------------------------------------------------------------
// Attention: out = softmax((q Wq^T + bq)(k Wk^T + bk)^T * inv_sqrt_d * mask) (v Wv^T + bv)
// B=8, T=2048, D=512.  All inputs fp32; internally bf16 MFMA with fp32 accum.
//
// ws layout (needs 50,331,648 B):
//   qp  [16384][512] bf16      (q @ Wq^T + bq)
//   kp  [16384][512] bf16
//   vpT [8][512][2048] bf16    (v @ Wv^T + bv, stored transposed per batch)
// ---------------------------------------------------------------------------

typedef __attribute__((ext_vector_type(4))) float  f32x4;
typedef __attribute__((ext_vector_type(8))) short  s16x8;
typedef __attribute__((ext_vector_type(8))) __bf16 bf16x8;

__device__ __forceinline__ f32x4 mfma16(s16x8 a, s16x8 b, f32x4 c) {
  return __builtin_amdgcn_mfma_f32_16x16x32_bf16(
      __builtin_bit_cast(bf16x8, a), __builtin_bit_cast(bf16x8, b), c, 0, 0, 0);
}

// round-to-nearest-even fp32 -> bf16 bits (inputs are finite here)
__device__ __forceinline__ unsigned short f2bf(float f) {
  unsigned u = __float_as_uint(f);
  return (unsigned short)((u + 0x7fffu + ((u >> 16) & 1u)) >> 16);
}

#define SCALE 0.044194173824159216f  // 1/sqrt(512)

// ---------------------------------------------------------------------------
// Projection GEMM:  z=0: qp = q Wq^T + bq   (out [t][e])
//                   z=1: kp = k Wk^T + bk   (out [t][e])
//                   z=2: vpT = (v Wv^T+bv)^T (out [e][t], A/B swapped so the
//                        MFMA C-layout stores coalesced along t)
// grid (256 token-tiles, 8 e-tiles, 3), block 256 (4 waves), tile 64x64, BK=64.
// ---------------------------------------------------------------------------
__global__ __launch_bounds__(256) void proj_kernel(
    const float* __restrict__ q,  const float* __restrict__ kk, const float* __restrict__ v,
    const float* __restrict__ Wq, const float* __restrict__ bq,
    const float* __restrict__ Wk, const float* __restrict__ bk,
    const float* __restrict__ Wv, const float* __restrict__ bv,
    unsigned short* __restrict__ qp, unsigned short* __restrict__ kp,
    unsigned short* __restrict__ vpT)
{
  const int z  = blockIdx.z;
  const int xt = blockIdx.x;   // token tile 0..255
  const int yt = blockIdx.y;   // e tile 0..7

  const float* Asrc; const float* Bsrc; const float* bias;
  int Arow0, Brow0;
  if (z == 0)      { Asrc = q;  Bsrc = Wq; bias = bq; Arow0 = xt * 64; Brow0 = yt * 64; }
  else if (z == 1) { Asrc = kk; Bsrc = Wk; bias = bk; Arow0 = xt * 64; Brow0 = yt * 64; }
  else             { Asrc = Wv; Bsrc = v;  bias = bv; Arow0 = yt * 64; Brow0 = xt * 64; }

  // +8 pad per 64-elem row: b128 fragment reads land 2-way (free) on banks
  __shared__ __align__(16) unsigned short At[64 * 72];
  __shared__ __align__(16) unsigned short Bt[64 * 72];

  const int tid  = threadIdx.x;
  const int lane = tid & 63;
  const int w    = tid >> 6;        // wave 0..3 -> rows w*16..w*16+15
  const int m    = lane & 15;
  const int quad = lane >> 4;

  f32x4 acc[4];
  #pragma unroll
  for (int i = 0; i < 4; i++) acc[i] = (f32x4){0.f, 0.f, 0.f, 0.f};

  const int srow = tid >> 2;         // 0..63
  const int scol = (tid & 3) * 16;   // 0/16/32/48

  for (int kc = 0; kc < 8; kc++) {
    __syncthreads();
    {
      unsigned short tmp[16];
      const float* g = Asrc + (size_t)(Arow0 + srow) * 512 + kc * 64 + scol;
      #pragma unroll
      for (int j = 0; j < 16; j += 4) {
        f32x4 f = *(const f32x4*)(g + j);
        tmp[j] = f2bf(f[0]); tmp[j+1] = f2bf(f[1]); tmp[j+2] = f2bf(f[2]); tmp[j+3] = f2bf(f[3]);
      }
      *(s16x8*)&At[srow * 72 + scol]     = *(s16x8*)&tmp[0];
      *(s16x8*)&At[srow * 72 + scol + 8] = *(s16x8*)&tmp[8];

      const float* g2 = Bsrc + (size_t)(Brow0 + srow) * 512 + kc * 64 + scol;
      #pragma unroll
      for (int j = 0; j < 16; j += 4) {
        f32x4 f = *(const f32x4*)(g2 + j);
        tmp[j] = f2bf(f[0]); tmp[j+1] = f2bf(f[1]); tmp[j+2] = f2bf(f[2]); tmp[j+3] = f2bf(f[3]);
      }
      *(s16x8*)&Bt[srow * 72 + scol]     = *(s16x8*)&tmp[0];
      *(s16x8*)&Bt[srow * 72 + scol + 8] = *(s16x8*)&tmp[8];
    }
    __syncthreads();

    #pragma unroll
    for (int ks = 0; ks < 2; ks++) {
      s16x8 af = *(const s16x8*)&At[(w * 16 + m) * 72 + ks * 32 + quad * 8];
      #pragma unroll
      for (int nb = 0; nb < 4; nb++) {
        s16x8 bf = *(const s16x8*)&Bt[(nb * 16 + m) * 72 + ks * 32 + quad * 8];
        acc[nb] = mfma16(af, bf, acc[nb]);
      }
    }
  }

  if (z < 2) {
    unsigned short* o = (z == 0) ? qp : kp;
    #pragma unroll
    for (int nb = 0; nb < 4; nb++) {
      int   e_g = yt * 64 + nb * 16 + m;
      float bb  = bias[e_g];
      #pragma unroll
      for (int r = 0; r < 4; r++) {
        int t_g = xt * 64 + w * 16 + quad * 4 + r;
        o[(size_t)t_g * 512 + e_g] = f2bf(acc[nb][r] + bb);
      }
    }
  } else {
    #pragma unroll
    for (int r = 0; r < 4; r++) {
      int   e_g = yt * 64 + w * 16 + quad * 4 + r;
      float bb  = bias[e_g];
      #pragma unroll
      for (int nb = 0; nb < 4; nb++) {
        int t_g = xt * 64 + nb * 16 + m;
        int bbi = t_g >> 11, ti = t_g & 2047;
        vpT[(size_t)bbi * 1048576 + (size_t)e_g * 2048 + ti] = f2bf(acc[nb][r] + bb);
      }
    }
  }
}

// ---------------------------------------------------------------------------
// Flash attention (no-max online softmax: logits bounded, fp32 exp safe).
// grid (64 q-tiles, 8 batches), block 128 (2 waves x 16 q-rows), BK=32 keys.
// LDS: KpL 32KiB (swizzled) + VpL 32KiB (swizzled) = 64KiB; P overlaps KpL
// (written only after the post-S barrier; KpL fully restaged each iter).
// ---------------------------------------------------------------------------
__global__ __launch_bounds__(128, 1) void flash_kernel(
    const unsigned short* __restrict__ qp, const unsigned short* __restrict__ kp,
    const unsigned short* __restrict__ vpT, const float* __restrict__ mask,
    float* __restrict__ out)
{
  const int b    = blockIdx.y;
  const int q0   = blockIdx.x * 32;
  const int tid  = threadIdx.x;
  const int lane = tid & 63;
  const int w    = tid >> 6;       // wave 0..1
  const int m    = lane & 15;
  const int quad = lane >> 4;

  __shared__ __align__(16) unsigned short KpL[32 * 512];   // [key][d] swizzled
  __shared__ __align__(16) unsigned short VpL[512 * 32];   // [d][key] swizzled
  unsigned short* PL = &KpL[w * 640];  // 16x40 bf16 per wave (pad->2-way reads)

  // Q fragments: 16 rows x 512, registers (64 VGPR)
  s16x8 qf[16];
  {
    const unsigned short* qb = qp + ((size_t)b * 2048 + q0 + w * 16 + m) * 512;
    #pragma unroll
    for (int ks = 0; ks < 16; ks++)
      qf[ks] = *(const s16x8*)(qb + ks * 32 + quad * 8);
  }

  f32x4 acc[32];
  #pragma unroll
  for (int i = 0; i < 32; i++) acc[i] = (f32x4){0.f, 0.f, 0.f, 0.f};
  float lsum[4] = {0.f, 0.f, 0.f, 0.f};

  // per-lane swizzled LDS element bases
  const int rotKe  = (quad + m) & 7;
  const int rotKo  = (quad + m + 4) & 7;
  const int kbaseE = m * 512 + rotKe * 8;               // + nb*8192 + (ks>>1)*64
  const int kbaseO = m * 512 + rotKo * 8;
  const int rotV   = ((m & 1) * 4 + (m >> 1) + quad) & 7;
  const int vbase  = (m & ~1) * 32 + rotV * 8;          // + nb*512

  const float* mbase = mask + ((size_t)b * 2048 + q0 + w * 16 + quad * 4) * 2048;

  #pragma unroll 1
  for (int kt = 0; kt < 64; kt++) {
    // prefetch mask values (independent of LDS; drain at staging barrier)
    float mv0[4], mv1[4];
    #pragma unroll
    for (int r = 0; r < 4; r++) {
      const float* mr = mbase + (size_t)r * 2048 + kt * 32;
      mv0[r] = mr[m];
      mv1[r] = mr[m + 16];
    }

    __syncthreads();  // prev iter's PV/P reads done before restage
    {
      const unsigned short* kg = kp + ((size_t)b * 2048 + kt * 32) * 512;
      #pragma unroll
      for (int i = 0; i < 16; i++) {
        int ci = i * 128 + tid;
        int row = ci >> 6, c = ci & 63;
        s16x8 d = *(const s16x8*)(kg + (size_t)row * 512 + c * 8);
        int slot = row * 512 + ((c & ~7) + (((c & 7) + row) & 7)) * 8;
        *(s16x8*)&KpL[slot] = d;
      }
      const unsigned short* vg = vpT + (size_t)b * 1048576 + kt * 32;
      #pragma unroll
      for (int i = 0; i < 16; i++) {
        int u = i * 128 + tid;
        int dd = u >> 2, kq = u & 3;
        s16x8 dv = *(const s16x8*)(vg + (size_t)dd * 2048 + kq * 8);
        int slot = (dd & ~1) * 32 + ((((dd & 1) * 4 + kq) + (dd >> 1)) & 7) * 8;
        *(s16x8*)&VpL[slot] = dv;
      }
    }
    __syncthreads();

    // ---- S = Qp Kp^T  (16 q-rows x 32 keys), 4 independent MFMA chains ----
    f32x4 s00 = (f32x4){0.f,0.f,0.f,0.f}, s01 = (f32x4){0.f,0.f,0.f,0.f};
    f32x4 s10 = (f32x4){0.f,0.f,0.f,0.f}, s11 = (f32x4){0.f,0.f,0.f,0.f};
    #pragma unroll
    for (int ks = 0; ks < 16; ks += 2) {
      s16x8 b0 = *(const s16x8*)&KpL[kbaseE + (ks >> 1) * 64];
      s16x8 b1 = *(const s16x8*)&KpL[8192 + kbaseE + (ks >> 1) * 64];
      s00 = mfma16(qf[ks], b0, s00);
      s10 = mfma16(qf[ks], b1, s10);
      s16x8 b2 = *(const s16x8*)&KpL[kbaseO + (ks >> 1) * 64];
      s16x8 b3 = *(const s16x8*)&KpL[8192 + kbaseO + (ks >> 1) * 64];
      s01 = mfma16(qf[ks + 1], b2, s01);
      s11 = mfma16(qf[ks + 1], b3, s11);
    }
    f32x4 sA = s00 + s01;   // keys kt*32 + m
    f32x4 sB = s10 + s11;   // keys kt*32 + 16 + m

    __syncthreads();  // all waves done reading KpL before P overwrites it

    // ---- dropout-mask * scale, exp, P -> LDS; accumulate row sums ----
    #pragma unroll
    for (int r = 0; r < 4; r++) {
      float p0 = __expf(sA[r] * (SCALE * mv0[r]));
      float p1 = __expf(sB[r] * (SCALE * mv1[r]));
      lsum[r] += p0 + p1;
      PL[(quad * 4 + r) * 40 + m]      = f2bf(p0);
      PL[(quad * 4 + r) * 40 + m + 16] = f2bf(p1);
    }

    // ---- O += P Vp  (A-frag: one contiguous b128 of own wave's P) ----
    s16x8 pf = *(const s16x8*)&PL[m * 40 + quad * 8];
    #pragma unroll
    for (int nb = 0; nb < 32; nb++) {
      s16x8 vf = *(const s16x8*)&VpL[vbase + nb * 512];
      acc[nb] = mfma16(pf, vf, acc[nb]);
    }
  }

  // row sums: reduce across the 16 lanes of each quad
  #pragma unroll
  for (int r = 0; r < 4; r++) {
    float t = lsum[r];
    t += __shfl_xor(t, 1);
    t += __shfl_xor(t, 2);
    t += __shfl_xor(t, 4);
    t += __shfl_xor(t, 8);
    lsum[r] = 1.0f / t;
  }

  float* ob = out + ((size_t)b * 2048 + q0 + w * 16 + quad * 4) * 512;
  #pragma unroll
  for (int nb = 0; nb < 32; nb++) {
    #pragma unroll
    for (int r = 0; r < 4; r++)
      ob[(size_t)r * 512 + nb * 16 + m] = acc[nb][r] * lsum[r];
  }
}

// ---------------------------------------------------------------------------
extern "C" void kernel_launch(void* const* d_in, const int* in_sizes, int n_in,
                              void* d_out, int out_size, void* d_ws, size_t ws_size,
                              hipStream_t stream)
{
  const float* q    = (const float*)d_in[0];
  const float* k    = (const float*)d_in[1];
  const float* v    = (const float*)d_in[2];
  const float* Wq   = (const float*)d_in[3];
  const float* bq   = (const float*)d_in[4];
  const float* Wk   = (const float*)d_in[5];
  const float* bk   = (const float*)d_in[6];
  const float* Wv   = (const float*)d_in[7];
  const float* bv   = (const float*)d_in[8];
  const float* mask = (const float*)d_in[9];
  float* out = (float*)d_out;

  unsigned short* qp  = (unsigned short*)d_ws;              // 16.78 MB
  unsigned short* kp  = qp + (size_t)16384 * 512;           // 16.78 MB
  unsigned short* vpT = kp + (size_t)16384 * 512;           // 16.78 MB
  // total ws needed: 50,331,648 bytes

  dim3 pg(256, 8, 3);
  proj_kernel<<<pg, dim3(256, 1, 1), 0, stream>>>(q, k, v, Wq, bq, Wk, bk, Wv, bv,
                                                  qp, kp, vpT);
  dim3 fg(64, 8, 1);
  flash_kernel<<<fg, dim3(128, 1, 1), 0, stream>>>(qp, kp, vpT, mask, out);
}

// Round 2
// 583.898 us; speedup vs baseline: 1.6678x; 1.6678x over previous
//
#include <hip/hip_runtime.h>

// ---------------------------------------------------------------------------
// Attention: out = softmax((q Wq^T + bq)(k Wk^T + bk)^T * inv_sqrt_d * mask) (v Wv^T + bv)
// B=8, T=2048, D=512.  fp32 I/O; bf16 MFMA, fp32 accum.
//
// ws layout (50,331,648 B):
//   qp  [16384][512] bf16
//   kp  [16384][512] bf16
//   vpT [b][kt=64][d=512][32] bf16   (k-tiled so each 32-key V tile is one
//                                     contiguous 32 KiB chunk for DMA)
// ---------------------------------------------------------------------------

typedef __attribute__((ext_vector_type(4))) float  f32x4;
typedef __attribute__((ext_vector_type(8))) short  s16x8;
typedef __attribute__((ext_vector_type(8))) __bf16 bf16x8;

#define AS1 __attribute__((address_space(1)))
#define AS3 __attribute__((address_space(3)))

__device__ __forceinline__ f32x4 mfma16(s16x8 a, s16x8 b, f32x4 c) {
  return __builtin_amdgcn_mfma_f32_16x16x32_bf16(
      __builtin_bit_cast(bf16x8, a), __builtin_bit_cast(bf16x8, b), c, 0, 0, 0);
}

__device__ __forceinline__ unsigned short f2bf(float f) {
  unsigned u = __float_as_uint(f);
  return (unsigned short)((u + 0x7fffu + ((u >> 16) & 1u)) >> 16);
}

// async global->LDS DMA, 16 B/lane; LDS base wave-uniform, HW adds lane*16
__device__ __forceinline__ void gld16(const unsigned short* g, unsigned short* l) {
  __builtin_amdgcn_global_load_lds((const AS1 unsigned int*)g,
                                   (AS3 unsigned int*)l, 16, 0, 0);
}

#define SCALE 0.044194173824159216f  // 1/sqrt(512)

// ---------------------------------------------------------------------------
// Projection GEMM. grid (2048, 3): x encodes (xt,yt) XCD-aware:
//   c = x&7 (XCD), j = x>>3, yt = j&7, xt = (j>>3)*8 + c
// so each XCD re-reads a given A-tile 8x from its own L2, not HBM.
// z=0: qp = q Wq^T + bq ; z=1: kp ; z=2: vpT = (v Wv^T + bv) k-tiled transposed
// ---------------------------------------------------------------------------
__global__ __launch_bounds__(256) void proj_kernel(
    const float* __restrict__ q,  const float* __restrict__ kk, const float* __restrict__ v,
    const float* __restrict__ Wq, const float* __restrict__ bq,
    const float* __restrict__ Wk, const float* __restrict__ bk,
    const float* __restrict__ Wv, const float* __restrict__ bv,
    unsigned short* __restrict__ qp, unsigned short* __restrict__ kp,
    unsigned short* __restrict__ vpT)
{
  const int z = blockIdx.y;
  const int x = blockIdx.x;
  const int c  = x & 7;
  const int j  = x >> 3;
  const int yt = j & 7;
  const int xt = (j >> 3) * 8 + c;

  const float* Asrc; const float* Bsrc; const float* bias;
  int Arow0, Brow0;
  if (z == 0)      { Asrc = q;  Bsrc = Wq; bias = bq; Arow0 = xt * 64; Brow0 = yt * 64; }
  else if (z == 1) { Asrc = kk; Bsrc = Wk; bias = bk; Arow0 = xt * 64; Brow0 = yt * 64; }
  else             { Asrc = Wv; Bsrc = v;  bias = bv; Arow0 = yt * 64; Brow0 = xt * 64; }

  __shared__ __align__(16) unsigned short At[64 * 72];
  __shared__ __align__(16) unsigned short Bt[64 * 72];

  const int tid  = threadIdx.x;
  const int lane = tid & 63;
  const int w    = tid >> 6;
  const int m    = lane & 15;
  const int quad = lane >> 4;

  f32x4 acc[4];
  #pragma unroll
  for (int i = 0; i < 4; i++) acc[i] = (f32x4){0.f, 0.f, 0.f, 0.f};

  const int srow = tid >> 2;
  const int scol = (tid & 3) * 16;

  for (int kc = 0; kc < 8; kc++) {
    __syncthreads();
    {
      unsigned short tmp[16];
      const float* g = Asrc + (size_t)(Arow0 + srow) * 512 + kc * 64 + scol;
      #pragma unroll
      for (int jj = 0; jj < 16; jj += 4) {
        f32x4 f = *(const f32x4*)(g + jj);
        tmp[jj] = f2bf(f[0]); tmp[jj+1] = f2bf(f[1]); tmp[jj+2] = f2bf(f[2]); tmp[jj+3] = f2bf(f[3]);
      }
      *(s16x8*)&At[srow * 72 + scol]     = *(s16x8*)&tmp[0];
      *(s16x8*)&At[srow * 72 + scol + 8] = *(s16x8*)&tmp[8];

      const float* g2 = Bsrc + (size_t)(Brow0 + srow) * 512 + kc * 64 + scol;
      #pragma unroll
      for (int jj = 0; jj < 16; jj += 4) {
        f32x4 f = *(const f32x4*)(g2 + jj);
        tmp[jj] = f2bf(f[0]); tmp[jj+1] = f2bf(f[1]); tmp[jj+2] = f2bf(f[2]); tmp[jj+3] = f2bf(f[3]);
      }
      *(s16x8*)&Bt[srow * 72 + scol]     = *(s16x8*)&tmp[0];
      *(s16x8*)&Bt[srow * 72 + scol + 8] = *(s16x8*)&tmp[8];
    }
    __syncthreads();

    #pragma unroll
    for (int ks = 0; ks < 2; ks++) {
      s16x8 af = *(const s16x8*)&At[(w * 16 + m) * 72 + ks * 32 + quad * 8];
      #pragma unroll
      for (int nb = 0; nb < 4; nb++) {
        s16x8 bf = *(const s16x8*)&Bt[(nb * 16 + m) * 72 + ks * 32 + quad * 8];
        acc[nb] = mfma16(af, bf, acc[nb]);
      }
    }
  }

  if (z < 2) {
    unsigned short* o = (z == 0) ? qp : kp;
    #pragma unroll
    for (int nb = 0; nb < 4; nb++) {
      int   e_g = yt * 64 + nb * 16 + m;
      float bb  = bias[e_g];
      #pragma unroll
      for (int r = 0; r < 4; r++) {
        int t_g = xt * 64 + w * 16 + quad * 4 + r;
        o[(size_t)t_g * 512 + e_g] = f2bf(acc[nb][r] + bb);
      }
    }
  } else {
    #pragma unroll
    for (int r = 0; r < 4; r++) {
      int   e_g = yt * 64 + w * 16 + quad * 4 + r;
      float bb  = bias[e_g];
      #pragma unroll
      for (int nb = 0; nb < 4; nb++) {
        int t_g  = xt * 64 + nb * 16 + m;
        int bbi  = t_g >> 11, ti = t_g & 2047;
        int ktil = ti >> 5,   kkq = ti & 31;
        vpT[(((size_t)bbi * 64 + ktil) * 512 + e_g) * 32 + kkq] = f2bf(acc[nb][r] + bb);
      }
    }
  }
}

// ---------------------------------------------------------------------------
// Flash attention, async double-buffered staging.
// grid 256 blocks: b = id&7 (one batch per XCD), q-tile = id>>3 (64 rows).
// block 256 = 4 waves x 16 q-rows. BK=32. LDS: K dbuf 64K + V dbuf 64K = 128K
// -> 1 block/CU. P (64x36 bf16) overlaps Kbuf[cur] (safe after barrier3).
// Pipeline per iter: barrier | mask+DMA(kt+1) | vmcnt(24) barrier | S |
// barrier | exp/P | barrier | PV.  No vmcnt(0) drains: prefetch stays in
// flight across barriers (raw s_barrier, not __syncthreads).
// ---------------------------------------------------------------------------
__global__ __launch_bounds__(256, 1) void flash_kernel(
    const unsigned short* __restrict__ qp, const unsigned short* __restrict__ kp,
    const unsigned short* __restrict__ vpT, const float* __restrict__ mask,
    float* __restrict__ out)
{
  const int id   = blockIdx.x;
  const int b    = id & 7;
  const int q0   = (id >> 3) * 64;
  const int tid  = threadIdx.x;
  const int lane = tid & 63;
  const int w    = tid >> 6;     // wave 0..3, owns q-rows w*16..+16 for S
  const int m    = lane & 15;
  const int quad = lane >> 4;
  const int p    = w >> 1;       // pair: shares P rows p*32..+32
  const int h    = w & 1;        // PV column half

  __shared__ __align__(16) unsigned short Kbuf[2][32 * 512];  // [key][d]
  __shared__ __align__(16) unsigned short Vbuf[2][512 * 32];  // [d][key]

  // Q fragments: 16 rows x 512 in registers (64 VGPR)
  s16x8 qf[16];
  {
    const unsigned short* qb = qp + ((size_t)b * 2048 + q0 + w * 16 + m) * 512;
    #pragma unroll
    for (int ks = 0; ks < 16; ks++)
      qf[ks] = *(const s16x8*)(qb + ks * 32 + quad * 8);
  }

  f32x4 accA[16], accB[16];
  #pragma unroll
  for (int i = 0; i < 16; i++) {
    accA[i] = (f32x4){0.f, 0.f, 0.f, 0.f};
    accB[i] = (f32x4){0.f, 0.f, 0.f, 0.f};
  }
  float lsum[4] = {0.f, 0.f, 0.f, 0.f};

  const unsigned short* kgb = kp  + (size_t)b * 2048 * 512;
  const unsigned short* vgb = vpT + (size_t)b * 64 * 16384;
  const float* mbase = mask + ((size_t)b * 2048 + q0 + w * 16 + quad * 4) * 2048;

  // prologue: DMA tile 0 (16 instrs/wave, 1 KiB each)
  #pragma unroll
  for (int i = 0; i < 8; i++) {
    int row = w * 8 + i;
    gld16(kgb + (size_t)row * 512 + lane * 8, &Kbuf[0][row * 512]);
  }
  #pragma unroll
  for (int i = 0; i < 8; i++) {
    int ch = w * 8 + i;
    gld16(vgb + (size_t)ch * 512 + lane * 8, &Vbuf[0][ch * 512]);
  }

  #pragma unroll 1
  for (int kt = 0; kt < 64; kt++) {
    const int cur = kt & 1;

    asm volatile("s_barrier" ::: "memory");  // waves done with iter kt-1

    // mask for this tile (plain loads; compiler waits before use in exp phase)
    float mv0[4], mv1[4];
    #pragma unroll
    for (int r = 0; r < 4; r++) {
      const float* mr = mbase + (size_t)r * 2048 + kt * 32;
      mv0[r] = mr[m];
      mv1[r] = mr[m + 16];
    }

    if (kt + 1 < 64) {
      const int nxt = cur ^ 1;
      const unsigned short* kg = kgb + (size_t)(kt + 1) * 32 * 512;
      #pragma unroll
      for (int i = 0; i < 8; i++) {
        int row = w * 8 + i;
        gld16(kg + (size_t)row * 512 + lane * 8, &Kbuf[nxt][row * 512]);
      }
      const unsigned short* vg = vgb + (size_t)(kt + 1) * 16384;
      #pragma unroll
      for (int i = 0; i < 8; i++) {
        int ch = w * 8 + i;
        gld16(vg + (size_t)ch * 512 + lane * 8, &Vbuf[nxt][ch * 512]);
      }
      // newest 24 = mask(kt) 8 + DMA(kt+1) 16 stay in flight; DMA(kt) drained
      asm volatile("s_waitcnt vmcnt(24)" ::: "memory");
    } else {
      asm volatile("s_waitcnt vmcnt(8)" ::: "memory");   // drain DMA(63)
    }
    asm volatile("s_barrier" ::: "memory");  // tile kt resident for all waves

    // ---- S = Qp Kp^T (own 16 rows x 32 keys) ----
    const unsigned short* Kc = &Kbuf[cur][0];
    f32x4 s00 = (f32x4){0.f,0.f,0.f,0.f}, s01 = (f32x4){0.f,0.f,0.f,0.f};
    f32x4 s10 = (f32x4){0.f,0.f,0.f,0.f}, s11 = (f32x4){0.f,0.f,0.f,0.f};
    #pragma unroll
    for (int ks = 0; ks < 16; ks += 2) {
      s16x8 b0 = *(const s16x8*)&Kc[(size_t)m * 512 + ks * 32 + quad * 8];
      s16x8 b1 = *(const s16x8*)&Kc[(size_t)(16 + m) * 512 + ks * 32 + quad * 8];
      s00 = mfma16(qf[ks], b0, s00);
      s10 = mfma16(qf[ks], b1, s10);
      s16x8 b2 = *(const s16x8*)&Kc[(size_t)m * 512 + (ks + 1) * 32 + quad * 8];
      s16x8 b3 = *(const s16x8*)&Kc[(size_t)(16 + m) * 512 + (ks + 1) * 32 + quad * 8];
      s01 = mfma16(qf[ks + 1], b2, s01);
      s11 = mfma16(qf[ks + 1], b3, s11);
    }
    f32x4 sA = s00 + s01;   // keys kt*32 + m
    f32x4 sB = s10 + s11;   // keys kt*32 + 16 + m

    asm volatile("s_barrier" ::: "memory");  // all S reads of Kbuf[cur] done

    // ---- mask*scale, exp, P -> LDS (shared across wave pair) ----
    unsigned short* PL = &Kbuf[cur][0];      // [64][36] bf16, overlaps K tile
    #pragma unroll
    for (int r = 0; r < 4; r++) {
      float p0 = __expf(sA[r] * (SCALE * mv0[r]));
      float p1 = __expf(sB[r] * (SCALE * mv1[r]));
      lsum[r] += p0 + p1;
      PL[(w * 16 + quad * 4 + r) * 36 + m]      = f2bf(p0);
      PL[(w * 16 + quad * 4 + r) * 36 + m + 16] = f2bf(p1);
    }
    asm volatile("s_waitcnt lgkmcnt(0)" ::: "memory");
    asm volatile("s_barrier" ::: "memory");  // P visible to partner wave

    // ---- O += P Vp : pair's 32 rows x own 256-col half ----
    const unsigned short* Vc = &Vbuf[cur][0];
    s16x8 pf0 = *(const s16x8*)&PL[(size_t)(p * 32 + m) * 36 + quad * 8];
    s16x8 pf1 = *(const s16x8*)&PL[(size_t)(p * 32 + 16 + m) * 36 + quad * 8];
    #pragma unroll
    for (int dt = 0; dt < 16; dt++) {
      s16x8 vf = *(const s16x8*)&Vc[(size_t)(h * 256 + dt * 16 + m) * 32 + quad * 8];
      accA[dt] = mfma16(pf0, vf, accA[dt]);
      accB[dt] = mfma16(pf1, vf, accB[dt]);
    }
  }

  // ---- row sums: reduce over 16 m-lanes, exchange via LDS ----
  #pragma unroll
  for (int r = 0; r < 4; r++) {
    float t = lsum[r];
    t += __shfl_xor(t, 1);
    t += __shfl_xor(t, 2);
    t += __shfl_xor(t, 4);
    t += __shfl_xor(t, 8);
    lsum[r] = t;
  }
  float* LS = (float*)&Vbuf[0][0];   // free: last PV read Vbuf[1] (kt=63)
  if (m == 0) {
    #pragma unroll
    for (int r = 0; r < 4; r++) LS[w * 16 + quad * 4 + r] = lsum[r];
  }
  asm volatile("s_waitcnt lgkmcnt(0)" ::: "memory");
  asm volatile("s_barrier" ::: "memory");

  float linvA[4], linvB[4];
  #pragma unroll
  for (int r = 0; r < 4; r++) {
    linvA[r] = 1.0f / LS[p * 32 + quad * 4 + r];
    linvB[r] = 1.0f / LS[p * 32 + 16 + quad * 4 + r];
  }

  float* ob = out + ((size_t)b * 2048 + q0 + p * 32 + quad * 4) * 512 + h * 256;
  #pragma unroll
  for (int dt = 0; dt < 16; dt++) {
    #pragma unroll
    for (int r = 0; r < 4; r++) {
      ob[(size_t)r * 512 + dt * 16 + m]        = accA[dt][r] * linvA[r];
      ob[(size_t)(16 + r) * 512 + dt * 16 + m] = accB[dt][r] * linvB[r];
    }
  }
}

// ---------------------------------------------------------------------------
extern "C" void kernel_launch(void* const* d_in, const int* in_sizes, int n_in,
                              void* d_out, int out_size, void* d_ws, size_t ws_size,
                              hipStream_t stream)
{
  const float* q    = (const float*)d_in[0];
  const float* k    = (const float*)d_in[1];
  const float* v    = (const float*)d_in[2];
  const float* Wq   = (const float*)d_in[3];
  const float* bq   = (const float*)d_in[4];
  const float* Wk   = (const float*)d_in[5];
  const float* bk   = (const float*)d_in[6];
  const float* Wv   = (const float*)d_in[7];
  const float* bv   = (const float*)d_in[8];
  const float* mask = (const float*)d_in[9];
  float* out = (float*)d_out;

  unsigned short* qp  = (unsigned short*)d_ws;
  unsigned short* kp  = qp + (size_t)16384 * 512;
  unsigned short* vpT = kp + (size_t)16384 * 512;

  dim3 pg(2048, 3, 1);
  proj_kernel<<<pg, dim3(256, 1, 1), 0, stream>>>(q, k, v, Wq, bq, Wk, bk, Wv, bv,
                                                  qp, kp, vpT);
  flash_kernel<<<dim3(256, 1, 1), dim3(256, 1, 1), 0, stream>>>(qp, kp, vpT, mask, out);
}

// Round 4
// 470.510 us; speedup vs baseline: 2.0697x; 1.2410x over previous
//
#include <hip/hip_runtime.h>
#include <hip/hip_bf16.h>

// ---------------------------------------------------------------------------
// Attention: out = softmax((q Wq^T + bq)(k Wk^T + bk)^T * inv_sqrt_d * mask) (v Wv^T + bv)
// B=8, T=2048, D=512.  fp32 I/O; bf16 MFMA, fp32 accum.
//
// ws layout (50,331,648 B, all LINEAR — swizzles live in DMA source addresses):
//   qp  [16384][512] bf16
//   kp  [16384][512] bf16
//   vpT [b][kt=64][d=512][32] bf16
// ---------------------------------------------------------------------------

typedef __attribute__((ext_vector_type(4))) float  f32x4;
typedef __attribute__((ext_vector_type(8))) short  s16x8;
typedef __attribute__((ext_vector_type(8))) __bf16 bf16x8;

#define AS1 __attribute__((address_space(1)))
#define AS3 __attribute__((address_space(3)))

__device__ __forceinline__ f32x4 mfma16(s16x8 a, s16x8 b, f32x4 c) {
  return __builtin_amdgcn_mfma_f32_16x16x32_bf16(
      __builtin_bit_cast(bf16x8, a), __builtin_bit_cast(bf16x8, b), c, 0, 0, 0);
}

__device__ __forceinline__ unsigned short f2bf(float f) {
  unsigned u = __float_as_uint(f);
  return (unsigned short)((u + 0x7fffu + ((u >> 16) & 1u)) >> 16);
}

// packed fp32x8 -> bf16x8 (RNE, v_cvt_pk_bf16_f32 path); memcpy instead of
// bit_cast: __hip_bfloat162 is not trivially copyable
__device__ __forceinline__ s16x8 pack8(f32x4 a, f32x4 b) {
  union { s16x8 v; unsigned int u[4]; } r;
  __hip_bfloat162 t0 = __float22bfloat162_rn(make_float2(a[0], a[1]));
  __hip_bfloat162 t1 = __float22bfloat162_rn(make_float2(a[2], a[3]));
  __hip_bfloat162 t2 = __float22bfloat162_rn(make_float2(b[0], b[1]));
  __hip_bfloat162 t3 = __float22bfloat162_rn(make_float2(b[2], b[3]));
  __builtin_memcpy(&r.u[0], &t0, 4);
  __builtin_memcpy(&r.u[1], &t1, 4);
  __builtin_memcpy(&r.u[2], &t2, 4);
  __builtin_memcpy(&r.u[3], &t3, 4);
  return r.v;
}

// async global->LDS DMA, 16 B/lane; LDS dst wave-uniform base + lane*16
__device__ __forceinline__ void gld16(const unsigned short* g, unsigned short* l) {
  __builtin_amdgcn_global_load_lds((const AS1 unsigned int*)g,
                                   (AS3 unsigned int*)l, 16, 0, 0);
}
__device__ __forceinline__ void gldf(const float* g, float* l) {
  __builtin_amdgcn_global_load_lds((const AS1 unsigned int*)g,
                                   (AS3 unsigned int*)l, 16, 0, 0);
}

#define SCALE 0.044194173824159216f  // 1/sqrt(512)

// ---------------------------------------------------------------------------
// Projection GEMM, m97-style: 128x128 tile, BK=32 (fp32 in LDS, convert at
// fragment read), dbuf + global_load_lds + fine vmcnt(8).
// z=0: qp = q Wq^T + bq ; z=1: kp ; z=2: vpT = (v Wv^T + bv), k-tiled transposed
// Grid 1536 linear; decode XCD-aware: c=id&7 so A-tile rereads hit own-XCD L2.
// ---------------------------------------------------------------------------
__global__ __launch_bounds__(256, 2) void proj_kernel(
    const float* __restrict__ q,  const float* __restrict__ kk, const float* __restrict__ v,
    const float* __restrict__ Wq, const float* __restrict__ bq,
    const float* __restrict__ Wk, const float* __restrict__ bk,
    const float* __restrict__ Wv, const float* __restrict__ bv,
    unsigned short* __restrict__ qp, unsigned short* __restrict__ kp,
    unsigned short* __restrict__ vpT)
{
  const int id = blockIdx.x;
  const int c  = id & 7;          // XCD (heuristic: linear id % 8)
  const int j  = id >> 3;         // 0..191
  const int z  = j >> 6;          // 0..2
  const int j2 = j & 63;
  int xt, yt;                     // xt: M-tile, yt: N-tile
  if (z < 2) { yt = j2 & 3; xt = (j2 >> 2) * 8 + c; }   // M=16384/128, N=512/128
  else       { xt = j2 & 3; yt = (j2 >> 2) * 8 + c; }   // M=512/128,  N=16384/128

  const float* Asrc; const float* Bsrc; const float* bias;
  if (z == 0)      { Asrc = q;  Bsrc = Wq; bias = bq; }
  else if (z == 1) { Asrc = kk; Bsrc = Wk; bias = bk; }
  else             { Asrc = Wv; Bsrc = v;  bias = bv; }
  const int Arow0 = xt * 128, Brow0 = yt * 128;
  const float* Ag = Asrc + (size_t)Arow0 * 512;
  const float* Bg = Bsrc + (size_t)Brow0 * 512;

  __shared__ __align__(16) float Abuf[2][128 * 32];   // 16 KB each
  __shared__ __align__(16) float Bbuf[2][128 * 32];   // total 64 KB -> 2 blk/CU

  const int tid  = threadIdx.x;
  const int lane = tid & 63;
  const int w    = tid >> 6;
  const int wr   = w >> 1, wc = w & 1;   // 2x2 wave grid, 64x64 each
  const int m    = lane & 15;
  const int quad = lane >> 4;

  // DMA source swizzle: 8 rows per instr; physical chunk l holds logical
  // chunk (l&7)^(row&7); row&7 == lane>>3 (row groups are 8-aligned)
  const int lr = lane >> 3;
  const int sw = ((lane & 7) ^ lr) * 4;   // fp32 elements

  f32x4 acc[4][4];
  #pragma unroll
  for (int i = 0; i < 4; i++)
    #pragma unroll
    for (int n = 0; n < 4; n++) acc[i][n] = (f32x4){0.f, 0.f, 0.f, 0.f};

  // prologue: stage kc=0
  #pragma unroll
  for (int i = 0; i < 4; i++) {
    int r0 = w * 32 + i * 8;
    gldf(Ag + (size_t)(r0 + lr) * 512 + sw, &Abuf[0][r0 * 32]);
  }
  #pragma unroll
  for (int i = 0; i < 4; i++) {
    int r0 = w * 32 + i * 8;
    gldf(Bg + (size_t)(r0 + lr) * 512 + sw, &Bbuf[0][r0 * 32]);
  }

  const int xrow = m & 7;   // frag-read swizzle key (frag row & 7 == m & 7)

  #pragma unroll 1
  for (int kc = 0; kc < 16; kc++) {
    const int cur = kc & 1;
    asm volatile("s_barrier" ::: "memory");   // all MFMA(kc-1) done -> safe to fill nxt
    if (kc < 15) {
      const int nxt = cur ^ 1;
      const size_t ko = (size_t)(kc + 1) * 32;
      #pragma unroll
      for (int i = 0; i < 4; i++) {
        int r0 = w * 32 + i * 8;
        gldf(Ag + (size_t)(r0 + lr) * 512 + ko + sw, &Abuf[nxt][r0 * 32]);
      }
      #pragma unroll
      for (int i = 0; i < 4; i++) {
        int r0 = w * 32 + i * 8;
        gldf(Bg + (size_t)(r0 + lr) * 512 + ko + sw, &Bbuf[nxt][r0 * 32]);
      }
      asm volatile("s_waitcnt vmcnt(8)" ::: "memory");   // drain DMA(kc), keep DMA(kc+1)
    } else {
      asm volatile("s_waitcnt vmcnt(0)" ::: "memory");
    }
    asm volatile("s_barrier" ::: "memory");   // tile kc resident

    const float* Ac = &Abuf[cur][0];
    const float* Bc = &Bbuf[cur][0];
    s16x8 af[4], bf[4];
    #pragma unroll
    for (int mt = 0; mt < 4; mt++) {
      int row = wr * 64 + mt * 16 + m;
      int p0 = ((quad * 2) ^ xrow) * 4, p1 = ((quad * 2 + 1) ^ xrow) * 4;
      f32x4 a = *(const f32x4*)(Ac + row * 32 + p0);
      f32x4 b = *(const f32x4*)(Ac + row * 32 + p1);
      af[mt] = pack8(a, b);
    }
    #pragma unroll
    for (int nt = 0; nt < 4; nt++) {
      int row = wc * 64 + nt * 16 + m;
      int p0 = ((quad * 2) ^ xrow) * 4, p1 = ((quad * 2 + 1) ^ xrow) * 4;
      f32x4 a = *(const f32x4*)(Bc + row * 32 + p0);
      f32x4 b = *(const f32x4*)(Bc + row * 32 + p1);
      bf[nt] = pack8(a, b);
    }
    #pragma unroll
    for (int mt = 0; mt < 4; mt++)
      #pragma unroll
      for (int nt = 0; nt < 4; nt++)
        acc[mt][nt] = mfma16(af[mt], bf[nt], acc[mt][nt]);
  }

  if (z < 2) {
    unsigned short* o = (z == 0) ? qp : kp;
    #pragma unroll
    for (int nt = 0; nt < 4; nt++) {
      int   e_g = Brow0 + wc * 64 + nt * 16 + m;
      float bb  = bias[e_g];
      #pragma unroll
      for (int mt = 0; mt < 4; mt++) {
        #pragma unroll
        for (int r = 0; r < 4; r++) {
          int t_g = Arow0 + wr * 64 + mt * 16 + quad * 4 + r;
          o[(size_t)t_g * 512 + e_g] = f2bf(acc[mt][nt][r] + bb);
        }
      }
    }
  } else {
    #pragma unroll
    for (int mt = 0; mt < 4; mt++) {
      #pragma unroll
      for (int r = 0; r < 4; r++) {
        int   e_g = Arow0 + wr * 64 + mt * 16 + quad * 4 + r;   // d index
        float bb  = bias[e_g];
        #pragma unroll
        for (int nt = 0; nt < 4; nt++) {
          int t_g = Brow0 + wc * 64 + nt * 16 + m;              // token
          int bbi = t_g >> 11, ti = t_g & 2047;
          int ktl = ti >> 5,   kq = ti & 31;
          vpT[(((size_t)bbi * 64 + ktl) * 512 + e_g) * 32 + kq] =
              f2bf(acc[mt][nt][r] + bb);
        }
      }
    }
  }
}

// ---------------------------------------------------------------------------
// Flash attention, async dbuf staging, swizzled-in-DMA LDS layouts.
// grid 256: b = id&7 (one batch per XCD: K+V fit its 4MB L2), q0 = (id>>3)*64.
// block 256 = 4 waves x 16 q-rows. BK=32.
// K tile: LDS phys chunk l of row r holds logical chunk l^(r&7)  -> S reads 2-way.
// V tile: per 16-row block, phys chunk p holds (dr=p>>2, c=(p&3)^((p>>3)&3))
//         -> PV reads 2-way.  P in dedicated 4.5 KB buffer (3 barriers/iter).
// ---------------------------------------------------------------------------
__global__ __launch_bounds__(256, 1) void flash_kernel(
    const unsigned short* __restrict__ qp, const unsigned short* __restrict__ kp,
    const unsigned short* __restrict__ vpT, const float* __restrict__ mask,
    float* __restrict__ out)
{
  const int id   = blockIdx.x;
  const int b    = id & 7;
  const int q0   = (id >> 3) * 64;
  const int tid  = threadIdx.x;
  const int lane = tid & 63;
  const int w    = tid >> 6;     // wave 0..3, owns q-rows w*16..+16 for S
  const int m    = lane & 15;
  const int quad = lane >> 4;
  const int p    = w >> 1;       // pair: shares P rows p*32..+32
  const int h    = w & 1;        // PV column half

  __shared__ __align__(16) unsigned short Kbuf[2][32 * 512];
  __shared__ __align__(16) unsigned short Vbuf[2][512 * 32];
  __shared__ __align__(16) unsigned short PL2[64 * 36];     // 4.5 KB

  // Q fragments: 16 rows x 512 in registers (qp is linear)
  s16x8 qf[16];
  {
    const unsigned short* qb = qp + ((size_t)b * 2048 + q0 + w * 16 + m) * 512;
    #pragma unroll
    for (int ks = 0; ks < 16; ks++)
      qf[ks] = *(const s16x8*)(qb + ks * 32 + quad * 8);
  }

  f32x4 accA[16], accB[16];
  #pragma unroll
  for (int i = 0; i < 16; i++) {
    accA[i] = (f32x4){0.f, 0.f, 0.f, 0.f};
    accB[i] = (f32x4){0.f, 0.f, 0.f, 0.f};
  }
  float lsum[4] = {0.f, 0.f, 0.f, 0.f};

  const unsigned short* kgb = kp  + (size_t)b * 2048 * 512;
  const unsigned short* vgb = vpT + (size_t)b * 64 * 16384;
  const float* mbase = mask + ((size_t)b * 2048 + q0 + w * 16 + quad * 4) * 2048;

  // per-lane swizzled offsets
  const int vdsw = (lane >> 2) * 32 + (((lane & 3) ^ ((lane >> 3) & 3)) * 8); // V DMA src
  const int oE   = ((quad ^ (m & 7)) & 7) * 8;          // S read, even ks
  const int oO   = (((quad ^ (m & 7)) ^ 4) & 7) * 8;    // S read, odd ks
  const int vb0  = h * 16 * 512 + (m * 4 + (quad ^ ((m >> 1) & 3))) * 8;  // PV read

  // prologue: DMA tile 0
  #pragma unroll
  for (int i = 0; i < 8; i++) {
    int r = w * 8 + i;
    gld16(kgb + (size_t)r * 512 + ((lane ^ i) * 8), &Kbuf[0][r * 512]);
  }
  #pragma unroll
  for (int i = 0; i < 8; i++) {
    int blk = w * 8 + i;
    gld16(vgb + (size_t)blk * 512 + vdsw, &Vbuf[0][blk * 512]);
  }

  #pragma unroll 1
  for (int kt = 0; kt < 64; kt++) {
    const int cur = kt & 1;

    asm volatile("s_barrier" ::: "memory");  // all waves done with iter kt-1

    // mask loads first (counted among the newest 24 at the vmcnt below)
    float mv0[4], mv1[4];
    #pragma unroll
    for (int r = 0; r < 4; r++) {
      const float* mr = mbase + (size_t)r * 2048 + kt * 32;
      mv0[r] = mr[m];
      mv1[r] = mr[m + 16];
    }

    if (kt + 1 < 64) {
      const int nxt = cur ^ 1;
      const unsigned short* kg = kgb + (size_t)(kt + 1) * 32 * 512;
      #pragma unroll
      for (int i = 0; i < 8; i++) {
        int r = w * 8 + i;
        gld16(kg + (size_t)r * 512 + ((lane ^ i) * 8), &Kbuf[nxt][r * 512]);
      }
      const unsigned short* vg = vgb + (size_t)(kt + 1) * 16384;
      #pragma unroll
      for (int i = 0; i < 8; i++) {
        int blk = w * 8 + i;
        gld16(vg + (size_t)blk * 512 + vdsw, &Vbuf[nxt][blk * 512]);
      }
      // keep mask(kt) 8 + DMA(kt+1) 16 in flight; drain DMA(kt)
      asm volatile("s_waitcnt vmcnt(24)" ::: "memory");
    } else {
      asm volatile("s_waitcnt vmcnt(8)" ::: "memory");
    }
    asm volatile("s_barrier" ::: "memory");  // tile kt resident for all waves

    // ---- S = Qp Kp^T (own 16 rows x 32 keys), swizzled K reads ----
    const unsigned short* Kc = &Kbuf[cur][0];
    f32x4 s00 = (f32x4){0.f,0.f,0.f,0.f}, s01 = (f32x4){0.f,0.f,0.f,0.f};
    f32x4 s10 = (f32x4){0.f,0.f,0.f,0.f}, s11 = (f32x4){0.f,0.f,0.f,0.f};
    #pragma unroll
    for (int ks = 0; ks < 16; ks += 2) {
      int o = (ks >> 1) * 64;
      s16x8 b0 = *(const s16x8*)&Kc[m * 512 + o + oE];
      s16x8 b1 = *(const s16x8*)&Kc[8192 + m * 512 + o + oE];
      s00 = mfma16(qf[ks], b0, s00);
      s10 = mfma16(qf[ks], b1, s10);
      s16x8 b2 = *(const s16x8*)&Kc[m * 512 + o + oO];
      s16x8 b3 = *(const s16x8*)&Kc[8192 + m * 512 + o + oO];
      s01 = mfma16(qf[ks + 1], b2, s01);
      s11 = mfma16(qf[ks + 1], b3, s11);
    }
    f32x4 sA = s00 + s01;   // keys kt*32 + m
    f32x4 sB = s10 + s11;   // keys kt*32 + 16 + m

    // ---- mask*scale, exp, P -> dedicated LDS (own rows; no barrier needed) ----
    #pragma unroll
    for (int r = 0; r < 4; r++) {
      float p0 = __expf(sA[r] * (SCALE * mv0[r]));
      float p1 = __expf(sB[r] * (SCALE * mv1[r]));
      lsum[r] += p0 + p1;
      PL2[(w * 16 + quad * 4 + r) * 36 + m]      = f2bf(p0);
      PL2[(w * 16 + quad * 4 + r) * 36 + m + 16] = f2bf(p1);
    }
    asm volatile("s_waitcnt lgkmcnt(0)" ::: "memory");
    asm volatile("s_barrier" ::: "memory");  // P visible to partner wave

    // ---- O += P Vp : pair's 32 rows x own 256-col half, swizzled V reads ----
    const unsigned short* Vc = &Vbuf[cur][0];
    s16x8 pf0 = *(const s16x8*)&PL2[(size_t)(p * 32 + m) * 36 + quad * 8];
    s16x8 pf1 = *(const s16x8*)&PL2[(size_t)(p * 32 + 16 + m) * 36 + quad * 8];
    #pragma unroll
    for (int dt = 0; dt < 16; dt++) {
      s16x8 vf = *(const s16x8*)&Vc[vb0 + dt * 512];
      accA[dt] = mfma16(pf0, vf, accA[dt]);
      accB[dt] = mfma16(pf1, vf, accB[dt]);
    }
  }

  // ---- row sums: reduce over 16 m-lanes, exchange via LDS ----
  #pragma unroll
  for (int r = 0; r < 4; r++) {
    float t = lsum[r];
    t += __shfl_xor(t, 1);
    t += __shfl_xor(t, 2);
    t += __shfl_xor(t, 4);
    t += __shfl_xor(t, 8);
    lsum[r] = t;
  }
  float* LS = (float*)&Vbuf[0][0];   // free: last PV (kt=63) read Vbuf[1]
  if (m == 0) {
    #pragma unroll
    for (int r = 0; r < 4; r++) LS[w * 16 + quad * 4 + r] = lsum[r];
  }
  asm volatile("s_waitcnt lgkmcnt(0)" ::: "memory");
  asm volatile("s_barrier" ::: "memory");

  float linvA[4], linvB[4];
  #pragma unroll
  for (int r = 0; r < 4; r++) {
    linvA[r] = 1.0f / LS[p * 32 + quad * 4 + r];
    linvB[r] = 1.0f / LS[p * 32 + 16 + quad * 4 + r];
  }

  float* ob = out + ((size_t)b * 2048 + q0 + p * 32 + quad * 4) * 512 + h * 256;
  #pragma unroll
  for (int dt = 0; dt < 16; dt++) {
    #pragma unroll
    for (int r = 0; r < 4; r++) {
      ob[(size_t)r * 512 + dt * 16 + m]        = accA[dt][r] * linvA[r];
      ob[(size_t)(16 + r) * 512 + dt * 16 + m] = accB[dt][r] * linvB[r];
    }
  }
}

// ---------------------------------------------------------------------------
extern "C" void kernel_launch(void* const* d_in, const int* in_sizes, int n_in,
                              void* d_out, int out_size, void* d_ws, size_t ws_size,
                              hipStream_t stream)
{
  const float* q    = (const float*)d_in[0];
  const float* k    = (const float*)d_in[1];
  const float* v    = (const float*)d_in[2];
  const float* Wq   = (const float*)d_in[3];
  const float* bq   = (const float*)d_in[4];
  const float* Wk   = (const float*)d_in[5];
  const float* bk   = (const float*)d_in[6];
  const float* Wv   = (const float*)d_in[7];
  const float* bv   = (const float*)d_in[8];
  const float* mask = (const float*)d_in[9];
  float* out = (float*)d_out;

  unsigned short* qp  = (unsigned short*)d_ws;
  unsigned short* kp  = qp + (size_t)16384 * 512;
  unsigned short* vpT = kp + (size_t)16384 * 512;

  proj_kernel<<<dim3(1536, 1, 1), dim3(256, 1, 1), 0, stream>>>(
      q, k, v, Wq, bq, Wk, bk, Wv, bv, qp, kp, vpT);
  flash_kernel<<<dim3(256, 1, 1), dim3(256, 1, 1), 0, stream>>>(
      qp, kp, vpT, mask, out);
}

// Round 5
// 436.067 us; speedup vs baseline: 2.2332x; 1.0790x over previous
//
#include <hip/hip_runtime.h>
#include <hip/hip_bf16.h>

// ---------------------------------------------------------------------------
// Attention: out = softmax((q Wq^T + bq)(k Wk^T + bk)^T * inv_sqrt_d * mask) (v Wv^T + bv)
// B=8, T=2048, D=512.  fp32 I/O; bf16 MFMA, fp32 accum.
//
// ws layout (50,331,648 B, all LINEAR — swizzles live in DMA source addresses):
//   qp  [16384][512] bf16
//   kp  [16384][512] bf16
//   vpT [b][kt=64][d=512][32] bf16
// ---------------------------------------------------------------------------

typedef __attribute__((ext_vector_type(4))) float  f32x4;
typedef __attribute__((ext_vector_type(8))) short  s16x8;
typedef __attribute__((ext_vector_type(8))) __bf16 bf16x8;

#define AS1 __attribute__((address_space(1)))
#define AS3 __attribute__((address_space(3)))

__device__ __forceinline__ f32x4 mfma16(s16x8 a, s16x8 b, f32x4 c) {
  return __builtin_amdgcn_mfma_f32_16x16x32_bf16(
      __builtin_bit_cast(bf16x8, a), __builtin_bit_cast(bf16x8, b), c, 0, 0, 0);
}

__device__ __forceinline__ unsigned short f2bf(float f) {
  unsigned u = __float_as_uint(f);
  return (unsigned short)((u + 0x7fffu + ((u >> 16) & 1u)) >> 16);
}

__device__ __forceinline__ s16x8 pack8(f32x4 a, f32x4 b) {
  union { s16x8 v; unsigned int u[4]; } r;
  __hip_bfloat162 t0 = __float22bfloat162_rn(make_float2(a[0], a[1]));
  __hip_bfloat162 t1 = __float22bfloat162_rn(make_float2(a[2], a[3]));
  __hip_bfloat162 t2 = __float22bfloat162_rn(make_float2(b[0], b[1]));
  __hip_bfloat162 t3 = __float22bfloat162_rn(make_float2(b[2], b[3]));
  __builtin_memcpy(&r.u[0], &t0, 4);
  __builtin_memcpy(&r.u[1], &t1, 4);
  __builtin_memcpy(&r.u[2], &t2, 4);
  __builtin_memcpy(&r.u[3], &t3, 4);
  return r.v;
}

__device__ __forceinline__ void gld16(const unsigned short* g, unsigned short* l) {
  __builtin_amdgcn_global_load_lds((const AS1 unsigned int*)g,
                                   (AS3 unsigned int*)l, 16, 0, 0);
}
__device__ __forceinline__ void gldf(const float* g, float* l) {
  __builtin_amdgcn_global_load_lds((const AS1 unsigned int*)g,
                                   (AS3 unsigned int*)l, 16, 0, 0);
}

#define SCALE 0.044194173824159216f  // 1/sqrt(512)

// ---------------------------------------------------------------------------
// Projection GEMM (unchanged from round 4 — passed, not in top-5 dispatches).
// ---------------------------------------------------------------------------
__global__ __launch_bounds__(256, 2) void proj_kernel(
    const float* __restrict__ q,  const float* __restrict__ kk, const float* __restrict__ v,
    const float* __restrict__ Wq, const float* __restrict__ bq,
    const float* __restrict__ Wk, const float* __restrict__ bk,
    const float* __restrict__ Wv, const float* __restrict__ bv,
    unsigned short* __restrict__ qp, unsigned short* __restrict__ kp,
    unsigned short* __restrict__ vpT)
{
  const int id = blockIdx.x;
  const int c  = id & 7;
  const int j  = id >> 3;
  const int z  = j >> 6;
  const int j2 = j & 63;
  int xt, yt;
  if (z < 2) { yt = j2 & 3; xt = (j2 >> 2) * 8 + c; }
  else       { xt = j2 & 3; yt = (j2 >> 2) * 8 + c; }

  const float* Asrc; const float* Bsrc; const float* bias;
  if (z == 0)      { Asrc = q;  Bsrc = Wq; bias = bq; }
  else if (z == 1) { Asrc = kk; Bsrc = Wk; bias = bk; }
  else             { Asrc = Wv; Bsrc = v;  bias = bv; }
  const int Arow0 = xt * 128, Brow0 = yt * 128;
  const float* Ag = Asrc + (size_t)Arow0 * 512;
  const float* Bg = Bsrc + (size_t)Brow0 * 512;

  __shared__ __align__(16) float Abuf[2][128 * 32];
  __shared__ __align__(16) float Bbuf[2][128 * 32];

  const int tid  = threadIdx.x;
  const int lane = tid & 63;
  const int w    = tid >> 6;
  const int wr   = w >> 1, wc = w & 1;
  const int m    = lane & 15;
  const int quad = lane >> 4;

  const int lr = lane >> 3;
  const int sw = ((lane & 7) ^ lr) * 4;

  f32x4 acc[4][4];
  #pragma unroll
  for (int i = 0; i < 4; i++)
    #pragma unroll
    for (int n = 0; n < 4; n++) acc[i][n] = (f32x4){0.f, 0.f, 0.f, 0.f};

  #pragma unroll
  for (int i = 0; i < 4; i++) {
    int r0 = w * 32 + i * 8;
    gldf(Ag + (size_t)(r0 + lr) * 512 + sw, &Abuf[0][r0 * 32]);
  }
  #pragma unroll
  for (int i = 0; i < 4; i++) {
    int r0 = w * 32 + i * 8;
    gldf(Bg + (size_t)(r0 + lr) * 512 + sw, &Bbuf[0][r0 * 32]);
  }

  const int xrow = m & 7;

  #pragma unroll 1
  for (int kc = 0; kc < 16; kc++) {
    const int cur = kc & 1;
    asm volatile("s_barrier" ::: "memory");
    if (kc < 15) {
      const int nxt = cur ^ 1;
      const size_t ko = (size_t)(kc + 1) * 32;
      #pragma unroll
      for (int i = 0; i < 4; i++) {
        int r0 = w * 32 + i * 8;
        gldf(Ag + (size_t)(r0 + lr) * 512 + ko + sw, &Abuf[nxt][r0 * 32]);
      }
      #pragma unroll
      for (int i = 0; i < 4; i++) {
        int r0 = w * 32 + i * 8;
        gldf(Bg + (size_t)(r0 + lr) * 512 + ko + sw, &Bbuf[nxt][r0 * 32]);
      }
      asm volatile("s_waitcnt vmcnt(8)" ::: "memory");
    } else {
      asm volatile("s_waitcnt vmcnt(0)" ::: "memory");
    }
    asm volatile("s_barrier" ::: "memory");

    const float* Ac = &Abuf[cur][0];
    const float* Bc = &Bbuf[cur][0];
    s16x8 af[4], bf[4];
    #pragma unroll
    for (int mt = 0; mt < 4; mt++) {
      int row = wr * 64 + mt * 16 + m;
      int p0 = ((quad * 2) ^ xrow) * 4, p1 = ((quad * 2 + 1) ^ xrow) * 4;
      f32x4 a = *(const f32x4*)(Ac + row * 32 + p0);
      f32x4 b = *(const f32x4*)(Ac + row * 32 + p1);
      af[mt] = pack8(a, b);
    }
    #pragma unroll
    for (int nt = 0; nt < 4; nt++) {
      int row = wc * 64 + nt * 16 + m;
      int p0 = ((quad * 2) ^ xrow) * 4, p1 = ((quad * 2 + 1) ^ xrow) * 4;
      f32x4 a = *(const f32x4*)(Bc + row * 32 + p0);
      f32x4 b = *(const f32x4*)(Bc + row * 32 + p1);
      bf[nt] = pack8(a, b);
    }
    #pragma unroll
    for (int mt = 0; mt < 4; mt++)
      #pragma unroll
      for (int nt = 0; nt < 4; nt++)
        acc[mt][nt] = mfma16(af[mt], bf[nt], acc[mt][nt]);
  }

  if (z < 2) {
    unsigned short* o = (z == 0) ? qp : kp;
    #pragma unroll
    for (int nt = 0; nt < 4; nt++) {
      int   e_g = Brow0 + wc * 64 + nt * 16 + m;
      float bb  = bias[e_g];
      #pragma unroll
      for (int mt = 0; mt < 4; mt++) {
        #pragma unroll
        for (int r = 0; r < 4; r++) {
          int t_g = Arow0 + wr * 64 + mt * 16 + quad * 4 + r;
          o[(size_t)t_g * 512 + e_g] = f2bf(acc[mt][nt][r] + bb);
        }
      }
    }
  } else {
    #pragma unroll
    for (int mt = 0; mt < 4; mt++) {
      #pragma unroll
      for (int r = 0; r < 4; r++) {
        int   e_g = Arow0 + wr * 64 + mt * 16 + quad * 4 + r;
        float bb  = bias[e_g];
        #pragma unroll
        for (int nt = 0; nt < 4; nt++) {
          int t_g = Brow0 + wc * 64 + nt * 16 + m;
          int bbi = t_g >> 11, ti = t_g & 2047;
          int ktl = ti >> 5,   kq = ti & 31;
          vpT[(((size_t)bbi * 64 + ktl) * 512 + e_g) * 32 + kq] =
              f2bf(acc[mt][nt][r] + bb);
        }
      }
    }
  }
}

// ---------------------------------------------------------------------------
// Flash attention v3: 512 threads = 8 waves (2 waves/SIMD), 64 q-rows/block.
// grid 256: b = id&7 (one batch per XCD), q0 = (id>>3)*64. BK=32.
// S:  wave w -> row-tile rw=w>>1 (16 rows), key-half kw=w&1 (16 keys): 16 MFMA,
//     16 KB LDS reads (half of round-4's per-wave volume).
// PV: wave w -> row-half rh=w>>2 (32 rows), d-quarter dq=w&3 (128 cols):
//     8 V-frags reused x2 row-tiles = 16 MFMA.
// Mask prefetched 1 iter ahead into regs (parity-unrolled) — exp never waits
// on HBM. 3 raw s_barriers/iter; DMA dbuf with vmcnt(12) (never 0 mid-loop).
// ---------------------------------------------------------------------------
__global__ __launch_bounds__(512, 2) void flash_kernel(
    const unsigned short* __restrict__ qp, const unsigned short* __restrict__ kp,
    const unsigned short* __restrict__ vpT, const float* __restrict__ mask,
    float* __restrict__ out)
{
  const int id   = blockIdx.x;
  const int b    = id & 7;
  const int q0   = (id >> 3) * 64;
  const int tid  = threadIdx.x;
  const int lane = tid & 63;
  const int w    = tid >> 6;     // wave 0..7
  const int m    = lane & 15;
  const int quad = lane >> 4;
  const int rw   = w >> 1;       // S row-tile 0..3
  const int kw   = w & 1;        // S key-half
  const int rh   = w >> 2;       // PV row-half 0..1
  const int dq   = w & 3;        // PV d-quarter 0..3

  __shared__ __align__(16) unsigned short Kbuf[2][32 * 512];  // 64 KB
  __shared__ __align__(16) unsigned short Vbuf[2][512 * 32];  // 64 KB
  __shared__ __align__(16) unsigned short PL2[64 * 36];       // 4.5 KB

  const unsigned short* kgb = kp  + (size_t)b * 2048 * 512;
  const unsigned short* vgb = vpT + (size_t)b * 64 * 16384;
  // mask rows for this wave's S tile: rows rw*16 + quad*4 + r, keys kw*16 + m
  const float* mbase = mask + ((size_t)b * 2048 + q0 + rw * 16 + quad * 4) * 2048
                     + kw * 16 + m;

  // per-lane swizzled LDS offsets (same families as round 4 — conflict-verified)
  const int oE  = ((quad ^ (m & 7)) & 7) * 8;          // S K-frag, even ks
  const int oO  = (((quad ^ (m & 7)) ^ 4) & 7) * 8;    // S K-frag, odd ks
  const int vsw = m * 32 + (quad ^ ((m >> 1) & 3)) * 8;                      // PV V-frag
  const int vdsw = (lane >> 2) * 32 + (((lane & 3) ^ ((lane >> 3) & 3)) * 8); // V DMA src
  const int krow = (kw * 16 + m) * 512;                // S K-frag row base

  // prologue: DMA tile 0 (4 K rows + 4 V chunks per wave), mask(0) prefetch
  #pragma unroll
  for (int i = 0; i < 4; i++) {
    int r = w * 4 + i;
    gld16(kgb + (size_t)r * 512 + ((lane ^ (r & 7)) * 8), &Kbuf[0][r * 512]);
  }
  #pragma unroll
  for (int i = 0; i < 4; i++) {
    int blk = w * 4 + i;
    gld16(vgb + (size_t)blk * 512 + vdsw, &Vbuf[0][blk * 512]);
  }
  float mvA[4], mvB[4];
  #pragma unroll
  for (int r = 0; r < 4; r++) mvA[r] = mbase[(size_t)r * 2048];

  // Q fragments: wave's 16 S-rows x 512 (64 VGPR)
  s16x8 qf[16];
  {
    const unsigned short* qb = qp + ((size_t)b * 2048 + q0 + rw * 16 + m) * 512;
    #pragma unroll
    for (int ks = 0; ks < 16; ks++)
      qf[ks] = *(const s16x8*)(qb + ks * 32 + quad * 8);
  }

  f32x4 acc0[8], acc1[8];
  #pragma unroll
  for (int i = 0; i < 8; i++) {
    acc0[i] = (f32x4){0.f, 0.f, 0.f, 0.f};
    acc1[i] = (f32x4){0.f, 0.f, 0.f, 0.f};
  }
  float lsum[4] = {0.f, 0.f, 0.f, 0.f};

#define FLASH_ITER(KT, MVU, MVL)                                               \
  {                                                                            \
    const int cur = (KT) & 1;                                                  \
    asm volatile("s_barrier" ::: "memory");                                    \
    if ((KT) + 1 < 64) {                                                       \
      const int nxt = cur ^ 1;                                                 \
      const unsigned short* kg = kgb + (size_t)((KT) + 1) * 32 * 512;          \
      _Pragma("unroll")                                                        \
      for (int i = 0; i < 4; i++) {                                            \
        int r = w * 4 + i;                                                     \
        gld16(kg + (size_t)r * 512 + ((lane ^ (r & 7)) * 8), &Kbuf[nxt][r * 512]); \
      }                                                                        \
      const unsigned short* vg = vgb + (size_t)((KT) + 1) * 16384;             \
      _Pragma("unroll")                                                        \
      for (int i = 0; i < 4; i++) {                                            \
        int blk = w * 4 + i;                                                   \
        gld16(vg + (size_t)blk * 512 + vdsw, &Vbuf[nxt][blk * 512]);           \
      }                                                                        \
      _Pragma("unroll")                                                        \
      for (int r = 0; r < 4; r++)                                              \
        MVL[r] = mbase[(size_t)r * 2048 + ((KT) + 1) * 32];                    \
      asm volatile("s_waitcnt vmcnt(12)" ::: "memory");                        \
    } else {                                                                   \
      asm volatile("s_waitcnt vmcnt(0)" ::: "memory");                         \
    }                                                                          \
    asm volatile("s_barrier" ::: "memory");                                    \
    /* S: own 16 rows x own 16-key half */                                     \
    const unsigned short* Kc = &Kbuf[cur][0];                                  \
    f32x4 s0 = (f32x4){0.f,0.f,0.f,0.f}, s1 = (f32x4){0.f,0.f,0.f,0.f};        \
    _Pragma("unroll")                                                          \
    for (int ks = 0; ks < 16; ks += 2) {                                       \
      int o = (ks >> 1) * 64;                                                  \
      s16x8 b0 = *(const s16x8*)&Kc[krow + o + oE];                            \
      s0 = mfma16(qf[ks], b0, s0);                                             \
      s16x8 b1 = *(const s16x8*)&Kc[krow + o + oO];                            \
      s1 = mfma16(qf[ks + 1], b1, s1);                                         \
    }                                                                          \
    f32x4 sA = s0 + s1;                                                        \
    /* exp with prefetched mask */                                             \
    _Pragma("unroll")                                                          \
    for (int r = 0; r < 4; r++) {                                              \
      float p0 = __expf(sA[r] * (SCALE * MVU[r]));                             \
      lsum[r] += p0;                                                           \
      PL2[(rw * 16 + quad * 4 + r) * 36 + kw * 16 + m] = f2bf(p0);             \
    }                                                                          \
    asm volatile("s_waitcnt lgkmcnt(0)" ::: "memory");                         \
    asm volatile("s_barrier" ::: "memory");                                    \
    /* PV: rows rh*32..+32, cols dq*128..+128 (V-frag reused x2) */            \
    const unsigned short* Vc = &Vbuf[cur][0];                                  \
    s16x8 pf0 = *(const s16x8*)&PL2[(rh * 32 + m) * 36 + quad * 8];            \
    s16x8 pf1 = *(const s16x8*)&PL2[(rh * 32 + 16 + m) * 36 + quad * 8];       \
    _Pragma("unroll")                                                          \
    for (int dt = 0; dt < 8; dt++) {                                           \
      s16x8 vf = *(const s16x8*)&Vc[(dq * 8 + dt) * 512 + vsw];                \
      acc0[dt] = mfma16(pf0, vf, acc0[dt]);                                    \
      acc1[dt] = mfma16(pf1, vf, acc1[dt]);                                    \
    }                                                                          \
  }

  #pragma unroll 1
  for (int kt2 = 0; kt2 < 64; kt2 += 2) {
    FLASH_ITER(kt2,     mvA, mvB)
    FLASH_ITER(kt2 + 1, mvB, mvA)
  }
#undef FLASH_ITER

  // ---- row-sum totals: reduce over 16 m-lanes, exchange via LDS ----
  #pragma unroll
  for (int r = 0; r < 4; r++) {
    float t = lsum[r];
    t += __shfl_xor(t, 1);
    t += __shfl_xor(t, 2);
    t += __shfl_xor(t, 4);
    t += __shfl_xor(t, 8);
    lsum[r] = t;
  }
  asm volatile("s_barrier" ::: "memory");   // all PV reads of PL2 done
  float* LSf = (float*)&PL2[0];             // [2][64] fp32
  if (m == 0) {
    #pragma unroll
    for (int r = 0; r < 4; r++) LSf[kw * 64 + rw * 16 + quad * 4 + r] = lsum[r];
  }
  asm volatile("s_waitcnt lgkmcnt(0)" ::: "memory");
  asm volatile("s_barrier" ::: "memory");

  #pragma unroll
  for (int t = 0; t < 2; t++) {
    #pragma unroll
    for (int r = 0; r < 4; r++) {
      int row = rh * 32 + t * 16 + quad * 4 + r;
      float linv = 1.0f / (LSf[row] + LSf[64 + row]);
      float* orow = out + ((size_t)b * 2048 + q0 + row) * 512 + dq * 128 + m;
      f32x4* a = t ? acc1 : acc0;
      #pragma unroll
      for (int dt = 0; dt < 8; dt++)
        orow[dt * 16] = a[dt][r] * linv;
    }
  }
}

// ---------------------------------------------------------------------------
extern "C" void kernel_launch(void* const* d_in, const int* in_sizes, int n_in,
                              void* d_out, int out_size, void* d_ws, size_t ws_size,
                              hipStream_t stream)
{
  const float* q    = (const float*)d_in[0];
  const float* k    = (const float*)d_in[1];
  const float* v    = (const float*)d_in[2];
  const float* Wq   = (const float*)d_in[3];
  const float* bq   = (const float*)d_in[4];
  const float* Wk   = (const float*)d_in[5];
  const float* bk   = (const float*)d_in[6];
  const float* Wv   = (const float*)d_in[7];
  const float* bv   = (const float*)d_in[8];
  const float* mask = (const float*)d_in[9];
  float* out = (float*)d_out;

  unsigned short* qp  = (unsigned short*)d_ws;
  unsigned short* kp  = qp + (size_t)16384 * 512;
  unsigned short* vpT = kp + (size_t)16384 * 512;

  proj_kernel<<<dim3(1536, 1, 1), dim3(256, 1, 1), 0, stream>>>(
      q, k, v, Wq, bq, Wk, bk, Wv, bv, qp, kp, vpT);
  flash_kernel<<<dim3(256, 1, 1), dim3(512, 1, 1), 0, stream>>>(
      qp, kp, vpT, mask, out);
}

// Round 6
// 422.174 us; speedup vs baseline: 2.3067x; 1.0329x over previous
//
#include <hip/hip_runtime.h>
#include <hip/hip_bf16.h>

// ---------------------------------------------------------------------------
// Attention: out = softmax((q Wq^T + bq)(k Wk^T + bk)^T * inv_sqrt_d * mask) (v Wv^T + bv)
// B=8, T=2048, D=512.  fp32 I/O; bf16 MFMA, fp32 accum.
//
// ws layout (50,331,648 B, all LINEAR — swizzles live in DMA source addresses):
//   qp  [16384][512] bf16
//   kp  [16384][512] bf16
//   vpT [b][kt=64][d=512][32] bf16
// ---------------------------------------------------------------------------

typedef __attribute__((ext_vector_type(4))) float  f32x4;
typedef __attribute__((ext_vector_type(8))) short  s16x8;
typedef __attribute__((ext_vector_type(8))) __bf16 bf16x8;

#define AS1 __attribute__((address_space(1)))
#define AS3 __attribute__((address_space(3)))

__device__ __forceinline__ f32x4 mfma16(s16x8 a, s16x8 b, f32x4 c) {
  return __builtin_amdgcn_mfma_f32_16x16x32_bf16(
      __builtin_bit_cast(bf16x8, a), __builtin_bit_cast(bf16x8, b), c, 0, 0, 0);
}

__device__ __forceinline__ unsigned short f2bf(float f) {
  unsigned u = __float_as_uint(f);
  return (unsigned short)((u + 0x7fffu + ((u >> 16) & 1u)) >> 16);
}

__device__ __forceinline__ s16x8 pack8(f32x4 a, f32x4 b) {
  union { s16x8 v; unsigned int u[4]; } r;
  __hip_bfloat162 t0 = __float22bfloat162_rn(make_float2(a[0], a[1]));
  __hip_bfloat162 t1 = __float22bfloat162_rn(make_float2(a[2], a[3]));
  __hip_bfloat162 t2 = __float22bfloat162_rn(make_float2(b[0], b[1]));
  __hip_bfloat162 t3 = __float22bfloat162_rn(make_float2(b[2], b[3]));
  __builtin_memcpy(&r.u[0], &t0, 4);
  __builtin_memcpy(&r.u[1], &t1, 4);
  __builtin_memcpy(&r.u[2], &t2, 4);
  __builtin_memcpy(&r.u[3], &t3, 4);
  return r.v;
}

__device__ __forceinline__ void gld16(const unsigned short* g, unsigned short* l) {
  __builtin_amdgcn_global_load_lds((const AS1 unsigned int*)g,
                                   (AS3 unsigned int*)l, 16, 0, 0);
}
__device__ __forceinline__ void gldf(const float* g, float* l) {
  __builtin_amdgcn_global_load_lds((const AS1 unsigned int*)g,
                                   (AS3 unsigned int*)l, 16, 0, 0);
}

#define SCALE 0.044194173824159216f  // 1/sqrt(512)

// ---------------------------------------------------------------------------
// Projection GEMM (unchanged from round 5).
// ---------------------------------------------------------------------------
__global__ __launch_bounds__(256, 2) void proj_kernel(
    const float* __restrict__ q,  const float* __restrict__ kk, const float* __restrict__ v,
    const float* __restrict__ Wq, const float* __restrict__ bq,
    const float* __restrict__ Wk, const float* __restrict__ bk,
    const float* __restrict__ Wv, const float* __restrict__ bv,
    unsigned short* __restrict__ qp, unsigned short* __restrict__ kp,
    unsigned short* __restrict__ vpT)
{
  const int id = blockIdx.x;
  const int c  = id & 7;
  const int j  = id >> 3;
  const int z  = j >> 6;
  const int j2 = j & 63;
  int xt, yt;
  if (z < 2) { yt = j2 & 3; xt = (j2 >> 2) * 8 + c; }
  else       { xt = j2 & 3; yt = (j2 >> 2) * 8 + c; }

  const float* Asrc; const float* Bsrc; const float* bias;
  if (z == 0)      { Asrc = q;  Bsrc = Wq; bias = bq; }
  else if (z == 1) { Asrc = kk; Bsrc = Wk; bias = bk; }
  else             { Asrc = Wv; Bsrc = v;  bias = bv; }
  const int Arow0 = xt * 128, Brow0 = yt * 128;
  const float* Ag = Asrc + (size_t)Arow0 * 512;
  const float* Bg = Bsrc + (size_t)Brow0 * 512;

  __shared__ __align__(16) float Abuf[2][128 * 32];
  __shared__ __align__(16) float Bbuf[2][128 * 32];

  const int tid  = threadIdx.x;
  const int lane = tid & 63;
  const int w    = tid >> 6;
  const int wr   = w >> 1, wc = w & 1;
  const int m    = lane & 15;
  const int quad = lane >> 4;

  const int lr = lane >> 3;
  const int sw = ((lane & 7) ^ lr) * 4;

  f32x4 acc[4][4];
  #pragma unroll
  for (int i = 0; i < 4; i++)
    #pragma unroll
    for (int n = 0; n < 4; n++) acc[i][n] = (f32x4){0.f, 0.f, 0.f, 0.f};

  #pragma unroll
  for (int i = 0; i < 4; i++) {
    int r0 = w * 32 + i * 8;
    gldf(Ag + (size_t)(r0 + lr) * 512 + sw, &Abuf[0][r0 * 32]);
  }
  #pragma unroll
  for (int i = 0; i < 4; i++) {
    int r0 = w * 32 + i * 8;
    gldf(Bg + (size_t)(r0 + lr) * 512 + sw, &Bbuf[0][r0 * 32]);
  }

  const int xrow = m & 7;

  #pragma unroll 1
  for (int kc = 0; kc < 16; kc++) {
    const int cur = kc & 1;
    asm volatile("s_barrier" ::: "memory");
    if (kc < 15) {
      const int nxt = cur ^ 1;
      const size_t ko = (size_t)(kc + 1) * 32;
      #pragma unroll
      for (int i = 0; i < 4; i++) {
        int r0 = w * 32 + i * 8;
        gldf(Ag + (size_t)(r0 + lr) * 512 + ko + sw, &Abuf[nxt][r0 * 32]);
      }
      #pragma unroll
      for (int i = 0; i < 4; i++) {
        int r0 = w * 32 + i * 8;
        gldf(Bg + (size_t)(r0 + lr) * 512 + ko + sw, &Bbuf[nxt][r0 * 32]);
      }
      asm volatile("s_waitcnt vmcnt(8)" ::: "memory");
    } else {
      asm volatile("s_waitcnt vmcnt(0)" ::: "memory");
    }
    asm volatile("s_barrier" ::: "memory");

    const float* Ac = &Abuf[cur][0];
    const float* Bc = &Bbuf[cur][0];
    s16x8 af[4], bf[4];
    #pragma unroll
    for (int mt = 0; mt < 4; mt++) {
      int row = wr * 64 + mt * 16 + m;
      int p0 = ((quad * 2) ^ xrow) * 4, p1 = ((quad * 2 + 1) ^ xrow) * 4;
      f32x4 a = *(const f32x4*)(Ac + row * 32 + p0);
      f32x4 b = *(const f32x4*)(Ac + row * 32 + p1);
      af[mt] = pack8(a, b);
    }
    #pragma unroll
    for (int nt = 0; nt < 4; nt++) {
      int row = wc * 64 + nt * 16 + m;
      int p0 = ((quad * 2) ^ xrow) * 4, p1 = ((quad * 2 + 1) ^ xrow) * 4;
      f32x4 a = *(const f32x4*)(Bc + row * 32 + p0);
      f32x4 b = *(const f32x4*)(Bc + row * 32 + p1);
      bf[nt] = pack8(a, b);
    }
    #pragma unroll
    for (int mt = 0; mt < 4; mt++)
      #pragma unroll
      for (int nt = 0; nt < 4; nt++)
        acc[mt][nt] = mfma16(af[mt], bf[nt], acc[mt][nt]);
  }

  if (z < 2) {
    unsigned short* o = (z == 0) ? qp : kp;
    #pragma unroll
    for (int nt = 0; nt < 4; nt++) {
      int   e_g = Brow0 + wc * 64 + nt * 16 + m;
      float bb  = bias[e_g];
      #pragma unroll
      for (int mt = 0; mt < 4; mt++) {
        #pragma unroll
        for (int r = 0; r < 4; r++) {
          int t_g = Arow0 + wr * 64 + mt * 16 + quad * 4 + r;
          o[(size_t)t_g * 512 + e_g] = f2bf(acc[mt][nt][r] + bb);
        }
      }
    }
  } else {
    #pragma unroll
    for (int mt = 0; mt < 4; mt++) {
      #pragma unroll
      for (int r = 0; r < 4; r++) {
        int   e_g = Arow0 + wr * 64 + mt * 16 + quad * 4 + r;
        float bb  = bias[e_g];
        #pragma unroll
        for (int nt = 0; nt < 4; nt++) {
          int t_g = Brow0 + wc * 64 + nt * 16 + m;
          int bbi = t_g >> 11, ti = t_g & 2047;
          int ktl = ti >> 5,   kq = ti & 31;
          vpT[(((size_t)bbi * 64 + ktl) * 512 + e_g) * 32 + kq] =
              f2bf(acc[mt][nt][r] + bb);
        }
      }
    }
  }
}

// ---------------------------------------------------------------------------
// Flash attention v4: producer-consumer wave specialization.
// 512 thr = 8 waves, 64 q-rows/block, BK=32, grid 256 (b=id&7 -> one batch/XCD).
// S-waves (w<4): (rsw=w&1 row-half, ksw=w>>1 key-half) each 32 rows x 16 keys,
//   two row-tiles SHARE K B-frags (K LDS redundancy 4x->2x). Q regs 128 VGPR.
// PV-waves (w>=4): dq=w&3 d-quarter, all 64 rows x 128 cols, lag 1 iter:
//   PV(kt-1) runs concurrently with S(kt). V redundancy 2x->1x. acc 128 VGPR.
// Q-frags (S) and O-acc (PV) ALIAS one f32x4 st[32] -> single 128-VGPR block.
// 2 barriers/iter; Pbuf parity-dbuf replaces the P-handoff barrier.
// vmcnt drains whole previous issue-window (S:16, PV:8) - order-robust.
// ---------------------------------------------------------------------------
__global__ __launch_bounds__(512, 2) void flash_kernel(
    const unsigned short* __restrict__ qp, const unsigned short* __restrict__ kp,
    const unsigned short* __restrict__ vpT, const float* __restrict__ mask,
    float* __restrict__ out)
{
  const int id   = blockIdx.x;
  const int b    = id & 7;
  const int q0   = (id >> 3) * 64;
  const int tid  = threadIdx.x;
  const int lane = tid & 63;
  const int w    = tid >> 6;
  const int m    = lane & 15;
  const int quad = lane >> 4;
  const bool isS = (w < 4);
  const int rsw  = w & 1;          // S: row-half (32 rows)
  const int ksw  = (w >> 1) & 1;   // S: key-half (16 keys)
  const int dq   = w & 3;          // PV: d-quarter (128 cols)

  __shared__ __align__(16) unsigned short Kbuf[2][32 * 512];  // 64 KB
  __shared__ __align__(16) unsigned short Vbuf[2][512 * 32];  // 64 KB
  __shared__ __align__(16) unsigned short Pbuf[2][64 * 36];   // 9 KB
  __shared__ float LSf[2][64];

  const unsigned short* kgb = kp  + (size_t)b * 2048 * 512;
  const unsigned short* vgb = vpT + (size_t)b * 64 * 16384;
  const float* mbase = mask + ((size_t)b * 2048 + q0 + rsw * 32 + quad * 4) * 2048
                     + ksw * 16 + m;

  // swizzled offsets (same families as r4/r5 — conflict-verified)
  const int oE   = ((quad ^ (m & 7)) & 7) * 8;
  const int oO   = (((quad ^ (m & 7)) ^ 4) & 7) * 8;
  const int vsw  = m * 32 + (quad ^ ((m >> 1) & 3)) * 8;
  const int vdsw = (lane >> 2) * 32 + (((lane & 3) ^ ((lane >> 3) & 3)) * 8);
  const int krow = (ksw * 16 + m) * 512;

  f32x4 st[32];              // S-waves: Q frags (bit-cast) | PV-waves: O acc
  float lsum[8] = {0.f, 0.f, 0.f, 0.f, 0.f, 0.f, 0.f, 0.f};
  float mvA[8], mvB[8];

  if (isS) {
    const unsigned short* qb = qp + ((size_t)b * 2048 + q0 + rsw * 32 + m) * 512;
    #pragma unroll
    for (int ks = 0; ks < 16; ks++) {
      s16x8 a0 = *(const s16x8*)(qb + ks * 32 + quad * 8);
      s16x8 a1 = *(const s16x8*)(qb + 16 * 512 + ks * 32 + quad * 8);
      st[ks]      = __builtin_bit_cast(f32x4, a0);
      st[16 + ks] = __builtin_bit_cast(f32x4, a1);
    }
  } else {
    #pragma unroll
    for (int i = 0; i < 32; i++) st[i] = (f32x4){0.f, 0.f, 0.f, 0.f};
  }

  // K(0) DMA (all waves) + mask(0) prefetch (S-waves)
  #pragma unroll
  for (int i = 0; i < 4; i++) {
    int r = w * 4 + i;
    gld16(kgb + (size_t)r * 512 + ((lane ^ (r & 7)) * 8), &Kbuf[0][r * 512]);
  }
  if (isS) {
    #pragma unroll
    for (int t = 0; t < 2; t++)
      #pragma unroll
      for (int r = 0; r < 4; r++)
        mvA[t * 4 + r] = mbase[(size_t)(t * 16 + r) * 2048];
  }
  asm volatile("s_waitcnt vmcnt(0)" ::: "memory");  // Q, K(0), mask(0) resident

#define FLASH_ITER(KT, MVU, MVL)                                               \
  {                                                                            \
    const int cur = (KT) & 1;                                                  \
    asm volatile("s_barrier" ::: "memory"); /* compute(KT-1) done all waves */ \
    /* issue window KT: K(KT+1), V(KT), mask(KT+1) */                          \
    if ((KT) + 1 < 64) {                                                       \
      const unsigned short* kg = kgb + (size_t)((KT) + 1) * 16384;             \
      _Pragma("unroll")                                                        \
      for (int i = 0; i < 4; i++) {                                            \
        int r = w * 4 + i;                                                     \
        gld16(kg + (size_t)r * 512 + ((lane ^ (r & 7)) * 8),                   \
              &Kbuf[cur ^ 1][r * 512]);                                        \
      }                                                                        \
    }                                                                          \
    {                                                                          \
      const unsigned short* vg = vgb + (size_t)(KT) * 16384;                   \
      _Pragma("unroll")                                                        \
      for (int i = 0; i < 4; i++) {                                            \
        int blk = w * 4 + i;                                                   \
        gld16(vg + (size_t)blk * 512 + vdsw, &Vbuf[cur][blk * 512]);           \
      }                                                                        \
    }                                                                          \
    if (isS && (KT) + 1 < 64) {                                                \
      _Pragma("unroll")                                                        \
      for (int t = 0; t < 2; t++)                                              \
        _Pragma("unroll")                                                      \
        for (int r = 0; r < 4; r++)                                            \
          MVL[t * 4 + r] = mbase[(size_t)(t * 16 + r) * 2048 + ((KT) + 1) * 32]; \
    }                                                                          \
    /* drain whole previous window (order-robust) */                           \
    if ((KT) < 63) {                                                           \
      if (isS) asm volatile("s_waitcnt vmcnt(16)" ::: "memory");               \
      else     asm volatile("s_waitcnt vmcnt(8)"  ::: "memory");               \
    } else {                                                                   \
      asm volatile("s_waitcnt vmcnt(4)" ::: "memory");                         \
    }                                                                          \
    asm volatile("s_barrier" ::: "memory"); /* K(KT),V(KT-1) resident */       \
    if (isS) {                                                                 \
      /* S(KT): 32 rows x 16 keys; K frags shared across row-tiles */          \
      const unsigned short* Kc = &Kbuf[cur][0];                                \
      f32x4 c0a = (f32x4){0.f,0.f,0.f,0.f}, c1a = (f32x4){0.f,0.f,0.f,0.f};    \
      f32x4 c0b = (f32x4){0.f,0.f,0.f,0.f}, c1b = (f32x4){0.f,0.f,0.f,0.f};    \
      _Pragma("unroll")                                                        \
      for (int ks = 0; ks < 16; ks += 2) {                                     \
        int o = (ks >> 1) * 64;                                                \
        s16x8 bE = *(const s16x8*)&Kc[krow + o + oE];                          \
        c0a = mfma16(__builtin_bit_cast(s16x8, st[ks]), bE, c0a);              \
        c0b = mfma16(__builtin_bit_cast(s16x8, st[16 + ks]), bE, c0b);         \
        s16x8 bO = *(const s16x8*)&Kc[krow + o + oO];                          \
        c1a = mfma16(__builtin_bit_cast(s16x8, st[ks + 1]), bO, c1a);          \
        c1b = mfma16(__builtin_bit_cast(s16x8, st[16 + ks + 1]), bO, c1b);     \
      }                                                                        \
      f32x4 sA = c0a + c1a;                                                    \
      f32x4 sB = c0b + c1b;                                                    \
      _Pragma("unroll")                                                        \
      for (int r = 0; r < 4; r++) {                                            \
        float p0 = __expf(sA[r] * (SCALE * MVU[r]));                           \
        float p1 = __expf(sB[r] * (SCALE * MVU[4 + r]));                       \
        lsum[r] += p0; lsum[4 + r] += p1;                                      \
        Pbuf[cur][(rsw * 32 + quad * 4 + r) * 36 + ksw * 16 + m]      = f2bf(p0); \
        Pbuf[cur][(rsw * 32 + 16 + quad * 4 + r) * 36 + ksw * 16 + m] = f2bf(p1); \
      }                                                                        \
      asm volatile("s_waitcnt lgkmcnt(0)" ::: "memory");                       \
    } else if ((KT) > 0) {                                                     \
      /* PV(KT-1): all 64 rows x 128 cols */                                   \
      const unsigned short* Vc = &Vbuf[cur ^ 1][0];                            \
      const unsigned short* Pc = &Pbuf[cur ^ 1][0];                            \
      s16x8 pf0 = *(const s16x8*)&Pc[(0 * 16 + m) * 36 + quad * 8];            \
      s16x8 pf1 = *(const s16x8*)&Pc[(1 * 16 + m) * 36 + quad * 8];            \
      s16x8 pf2 = *(const s16x8*)&Pc[(2 * 16 + m) * 36 + quad * 8];            \
      s16x8 pf3 = *(const s16x8*)&Pc[(3 * 16 + m) * 36 + quad * 8];            \
      _Pragma("unroll")                                                        \
      for (int dt = 0; dt < 8; dt++) {                                         \
        s16x8 vf = *(const s16x8*)&Vc[(dq * 8 + dt) * 512 + vsw];              \
        st[dt]      = mfma16(pf0, vf, st[dt]);                                 \
        st[8 + dt]  = mfma16(pf1, vf, st[8 + dt]);                             \
        st[16 + dt] = mfma16(pf2, vf, st[16 + dt]);                            \
        st[24 + dt] = mfma16(pf3, vf, st[24 + dt]);                            \
      }                                                                        \
    }                                                                          \
  }

  #pragma unroll 1
  for (int kt2 = 0; kt2 < 64; kt2 += 2) {
    FLASH_ITER(kt2,     mvA, mvB)
    FLASH_ITER(kt2 + 1, mvB, mvA)
  }
#undef FLASH_ITER

  // ---- epilogue: PV(63) + lsum exchange + normalize + store ----
  asm volatile("s_waitcnt vmcnt(0)" ::: "memory");   // V(63) resident
  asm volatile("s_barrier" ::: "memory");            // P(63) visible

  if (!isS) {
    const unsigned short* Vc = &Vbuf[1][0];
    const unsigned short* Pc = &Pbuf[1][0];
    s16x8 pf0 = *(const s16x8*)&Pc[(0 * 16 + m) * 36 + quad * 8];
    s16x8 pf1 = *(const s16x8*)&Pc[(1 * 16 + m) * 36 + quad * 8];
    s16x8 pf2 = *(const s16x8*)&Pc[(2 * 16 + m) * 36 + quad * 8];
    s16x8 pf3 = *(const s16x8*)&Pc[(3 * 16 + m) * 36 + quad * 8];
    #pragma unroll
    for (int dt = 0; dt < 8; dt++) {
      s16x8 vf = *(const s16x8*)&Vc[(dq * 8 + dt) * 512 + vsw];
      st[dt]      = mfma16(pf0, vf, st[dt]);
      st[8 + dt]  = mfma16(pf1, vf, st[8 + dt]);
      st[16 + dt] = mfma16(pf2, vf, st[16 + dt]);
      st[24 + dt] = mfma16(pf3, vf, st[24 + dt]);
    }
  } else {
    #pragma unroll
    for (int i = 0; i < 8; i++) {
      float t = lsum[i];
      t += __shfl_xor(t, 1);
      t += __shfl_xor(t, 2);
      t += __shfl_xor(t, 4);
      t += __shfl_xor(t, 8);
      lsum[i] = t;
    }
    if (m == 0) {
      #pragma unroll
      for (int t = 0; t < 2; t++)
        #pragma unroll
        for (int r = 0; r < 4; r++)
          LSf[ksw][rsw * 32 + t * 16 + quad * 4 + r] = lsum[t * 4 + r];
    }
    asm volatile("s_waitcnt lgkmcnt(0)" ::: "memory");
  }
  asm volatile("s_barrier" ::: "memory");

  if (!isS) {
    #pragma unroll
    for (int t = 0; t < 4; t++) {
      #pragma unroll
      for (int r = 0; r < 4; r++) {
        int row = t * 16 + quad * 4 + r;
        float linv = 1.0f / (LSf[0][row] + LSf[1][row]);
        float* orow = out + ((size_t)b * 2048 + q0 + row) * 512 + dq * 128 + m;
        #pragma unroll
        for (int dt = 0; dt < 8; dt++)
          orow[dt * 16] = st[t * 8 + dt][r] * linv;
      }
    }
  }
}

// ---------------------------------------------------------------------------
extern "C" void kernel_launch(void* const* d_in, const int* in_sizes, int n_in,
                              void* d_out, int out_size, void* d_ws, size_t ws_size,
                              hipStream_t stream)
{
  const float* q    = (const float*)d_in[0];
  const float* k    = (const float*)d_in[1];
  const float* v    = (const float*)d_in[2];
  const float* Wq   = (const float*)d_in[3];
  const float* bq   = (const float*)d_in[4];
  const float* Wk   = (const float*)d_in[5];
  const float* bk   = (const float*)d_in[6];
  const float* Wv   = (const float*)d_in[7];
  const float* bv   = (const float*)d_in[8];
  const float* mask = (const float*)d_in[9];
  float* out = (float*)d_out;

  unsigned short* qp  = (unsigned short*)d_ws;
  unsigned short* kp  = qp + (size_t)16384 * 512;
  unsigned short* vpT = kp + (size_t)16384 * 512;

  proj_kernel<<<dim3(1536, 1, 1), dim3(256, 1, 1), 0, stream>>>(
      q, k, v, Wq, bq, Wk, bk, Wv, bv, qp, kp, vpT);
  flash_kernel<<<dim3(256, 1, 1), dim3(512, 1, 1), 0, stream>>>(
      qp, kp, vpT, mask, out);
}